// Round 10
// baseline (515.661 us; speedup 1.0000x reference)
//
#include <hip/hip_runtime.h>

#define NNODES 50000
#define NEDGES 800000
#define F_IN   128
#define HID    256
#define NOUT   40
#define NBLK_SCAN ((NNODES + 255) / 256)  // 196
#define NBLK_CAST 6250                     // 50000*128/4/256
#define NBLK_DEG  2048                     // partitioned: 256 chunks x 8 groups
#define NBLK_PREP 432                      // 128 (W1) + 256 (W2) + 48 (Wc)
#define EDGE_CHUNK 3125                    // 800000 / 256
#define NODES_PER_G 6250                   // 50000 / 8
#define NCHUNK_AGG 1563                    // ceil(50000 / 32)

typedef __attribute__((ext_vector_type(8))) _Float16 f16x8;
typedef __attribute__((ext_vector_type(4))) float f32x4;

__device__ __forceinline__ unsigned short f2h(float f) {
  return __builtin_bit_cast(unsigned short, (_Float16)f);
}
__device__ __forceinline__ float h2f(unsigned short u) {
  return (float)__builtin_bit_cast(_Float16, u);
}

// ------- fused: x->fp16 SLICED cast | XCD-local degree | weight transpose ---
// Sliced layout: [slice][node][32 feats], slice = feat >> 5. Slab = 3.2 MB.

__global__ __launch_bounds__(256) void k_pre(const float* __restrict__ X,
                                             unsigned short* __restrict__ Xh,
                                             const int* __restrict__ dst,
                                             int* __restrict__ count,
                                             const float* __restrict__ W1,
                                             const float* __restrict__ W2,
                                             const float* __restrict__ Wc,
                                             unsigned short* __restrict__ T1,
                                             unsigned short* __restrict__ T2,
                                             unsigned short* __restrict__ Tc) {
  int b = blockIdx.x, t = threadIdx.x;
  if (b < NBLK_CAST) {
    int i = b * 256 + t;                 // float4 unit; 32 per node row
    int node = i >> 5, c = i & 31;       // c: 4-feat chunk within row
    int slab = c >> 3, off = (c & 7) * 4;
    float4 v = *reinterpret_cast<const float4*>(X + (size_t)i * 4);
    ushort4 o;
    o.x = f2h(v.x); o.y = f2h(v.y); o.z = f2h(v.z); o.w = f2h(v.w);
    *reinterpret_cast<ushort4*>(Xh + (size_t)slab * (NNODES * 32) +
                                (size_t)node * 32 + off) = o;
  } else if (b < NBLK_CAST + NBLK_DEG) {
    int db = b - NBLK_CAST;
    int g = b & 7;                 // hardware XCD (round-robin heuristic)
    int chunk = db >> 3;           // 0..255
    int lo = g * NODES_PER_G, hi = lo + NODES_PER_G;
    int base = chunk * EDGE_CHUNK;
    for (int i = base + t; i < base + EDGE_CHUNK; i += 256) {
      int d = dst[i];
      if (d >= lo && d < hi) atomicAdd(&count[d], 1);
    }
  } else {
    int pb = b - NBLK_CAST - NBLK_DEG;  // 0..431
    if (pb < 128) {                     // W1 [128][256] -> T1 [256][128]
      int idx = pb * 256 + t;
      int n = idx >> 7, k = idx & 127;
      T1[idx] = f2h(W1[(size_t)k * HID + n]);
    } else if (pb < 384) {              // W2 [256][256] -> T2 [256][256]
      int idx = (pb - 128) * 256 + t;
      int n = idx >> 8, k = idx & 255;
      T2[idx] = f2h(W2[(size_t)k * HID + n]);
    } else {                            // Wc [256][40] -> Tc [48][256] zero-pad
      int idx = (pb - 384) * 256 + t;
      int n = idx >> 8, k = idx & 255;
      float v = (n < NOUT) ? Wc[(size_t)k * NOUT + n] : 0.f;
      Tc[idx] = f2h(v);
    }
  }
}

// ---------------- CSR scan ----------------

__global__ __launch_bounds__(256) void k_scan1(const int* __restrict__ count,
                                               int* __restrict__ rowstart,
                                               int* __restrict__ bsum,
                                               float* __restrict__ dinv) {
  __shared__ int tmp[256];
  int t = threadIdx.x;
  int i = blockIdx.x * 256 + t;
  int v = (i < NNODES) ? count[i] : 0;
  if (i < NNODES) dinv[i] = rsqrtf((float)(v + 1));  // +1 self-loop
  tmp[t] = v;
  __syncthreads();
  for (int off = 1; off < 256; off <<= 1) {
    int x = (t >= off) ? tmp[t - off] : 0;
    __syncthreads();
    tmp[t] += x;
    __syncthreads();
  }
  if (i < NNODES) rowstart[i] = tmp[t] - v;  // exclusive within block
  if (t == 255) bsum[blockIdx.x] = tmp[255];
}

__global__ __launch_bounds__(256) void k_scan2(const int* __restrict__ bsum,
                                               int* __restrict__ boff) {
  __shared__ int tmp[256];
  int t = threadIdx.x;
  int v = (t < NBLK_SCAN) ? bsum[t] : 0;
  tmp[t] = v;
  __syncthreads();
  for (int off = 1; off < 256; off <<= 1) {
    int x = (t >= off) ? tmp[t - off] : 0;
    __syncthreads();
    tmp[t] += x;
    __syncthreads();
  }
  if (t < NBLK_SCAN) boff[t] = tmp[t] - v;  // exclusive
}

// ---------------- XCD-local scatter ----------------

__global__ __launch_bounds__(256) void k_scatter(const int* __restrict__ src,
                                                 const int* __restrict__ dst,
                                                 const int* __restrict__ rowstart,
                                                 const int* __restrict__ boff,
                                                 int* __restrict__ cursor,
                                                 int* __restrict__ csr) {
  int g = blockIdx.x & 7;
  int chunk = blockIdx.x >> 3;
  int lo = g * NODES_PER_G, hi = lo + NODES_PER_G;
  int base = chunk * EDGE_CHUNK;
  for (int i = base + threadIdx.x; i < base + EDGE_CHUNK; i += 256) {
    int d = dst[i];
    if (d >= lo && d < hi) {
      int p = rowstart[d] + boff[d >> 8] + atomicAdd(&cursor[d], 1);
      csr[p] = src[i];
    }
  }
}

// ---------------- feature-sliced XCD-resident aggregation ----------------
// X,Y sliced [NSLICE][N][32] fp16. Blocks with blockIdx&(NSLICE-1)==g touch
// only slab g (3.2 MB -> one XCD's L2). 8-lane groups, 8 edges per wave-pass,
// shfl_xor tree reduce. nt loads for csr (stream), nt stores for Y (protect
// slab residency). Wrong XCD mapping degrades speed only, never correctness.

template <int NSLICE>
__global__ __launch_bounds__(256) void k_aggs(const unsigned short* __restrict__ X,
                                              const int* __restrict__ rowstart,
                                              const int* __restrict__ boff,
                                              const int* __restrict__ csr,
                                              const float* __restrict__ dinv,
                                              unsigned short* __restrict__ Y) {
  constexpr int SSH = (NSLICE == 8) ? 3 : 2;
  int slice = blockIdx.x & (NSLICE - 1);
  int chunk = blockIdx.x >> SSH;
  const unsigned short* Xs = X + (size_t)slice * (NNODES * 32);
  unsigned short* Ys = Y + (size_t)slice * (NNODES * 32);
  int wave = threadIdx.x >> 6, lane = threadIdx.x & 63;
  int grp = lane >> 3, l8 = lane & 7;
  int n0 = (chunk * 4 + wave) * 8;
  for (int ni = 0; ni < 8; ni++) {
    int node = n0 + ni;
    if (node >= NNODES) return;
    float di = dinv[node];
    int e = rowstart[node] + boff[node >> 8];
    int end = (node + 1 < NNODES) ? rowstart[node + 1] + boff[(node + 1) >> 8] : NEDGES;
    float a0 = 0.f, a1 = 0.f, a2 = 0.f, a3 = 0.f;
    for (; e + 16 <= end; e += 16) {  // 2x8 edges in flight
      int sA = __builtin_nontemporal_load(&csr[e + grp]);
      int sB = __builtin_nontemporal_load(&csr[e + 8 + grp]);
      float wA = dinv[sA] * di, wB = dinv[sB] * di;
      uint2 vA = *reinterpret_cast<const uint2*>(Xs + (size_t)sA * 32 + l8 * 4);
      uint2 vB = *reinterpret_cast<const uint2*>(Xs + (size_t)sB * 32 + l8 * 4);
      a0 = fmaf(h2f((unsigned short)vA.x), wA, a0);
      a1 = fmaf(h2f((unsigned short)(vA.x >> 16)), wA, a1);
      a2 = fmaf(h2f((unsigned short)vA.y), wA, a2);
      a3 = fmaf(h2f((unsigned short)(vA.y >> 16)), wA, a3);
      a0 = fmaf(h2f((unsigned short)vB.x), wB, a0);
      a1 = fmaf(h2f((unsigned short)(vB.x >> 16)), wB, a1);
      a2 = fmaf(h2f((unsigned short)vB.y), wB, a2);
      a3 = fmaf(h2f((unsigned short)(vB.y >> 16)), wB, a3);
    }
    for (; e + 8 <= end; e += 8) {
      int s = __builtin_nontemporal_load(&csr[e + grp]);
      float w = dinv[s] * di;
      uint2 v = *reinterpret_cast<const uint2*>(Xs + (size_t)s * 32 + l8 * 4);
      a0 = fmaf(h2f((unsigned short)v.x), w, a0);
      a1 = fmaf(h2f((unsigned short)(v.x >> 16)), w, a1);
      a2 = fmaf(h2f((unsigned short)v.y), w, a2);
      a3 = fmaf(h2f((unsigned short)(v.y >> 16)), w, a3);
    }
    int rem = end - e;
    if (rem > 0) {  // 1..7 leftover edges; inactive groups use weight 0
      int s = __builtin_nontemporal_load(&csr[e + (grp < rem ? grp : 0)]);
      float w = (grp < rem) ? dinv[s] * di : 0.f;
      uint2 v = *reinterpret_cast<const uint2*>(Xs + (size_t)s * 32 + l8 * 4);
      a0 = fmaf(h2f((unsigned short)v.x), w, a0);
      a1 = fmaf(h2f((unsigned short)(v.x >> 16)), w, a1);
      a2 = fmaf(h2f((unsigned short)v.y), w, a2);
      a3 = fmaf(h2f((unsigned short)(v.y >> 16)), w, a3);
    }
#pragma unroll
    for (int off = 8; off < 64; off <<= 1) {
      a0 += __shfl_xor(a0, off);
      a1 += __shfl_xor(a1, off);
      a2 += __shfl_xor(a2, off);
      a3 += __shfl_xor(a3, off);
    }
    if (grp == 0) {  // lanes 0-7: add self-loop, write 64B contiguous
      uint2 v = *reinterpret_cast<const uint2*>(Xs + (size_t)node * 32 + l8 * 4);
      float dd = di * di;
      a0 = fmaf(h2f((unsigned short)v.x), dd, a0);
      a1 = fmaf(h2f((unsigned short)(v.x >> 16)), dd, a1);
      a2 = fmaf(h2f((unsigned short)v.y), dd, a2);
      a3 = fmaf(h2f((unsigned short)(v.y >> 16)), dd, a3);
      unsigned long long o =
          (unsigned long long)((unsigned)f2h(a0) | ((unsigned)f2h(a1) << 16)) |
          ((unsigned long long)((unsigned)f2h(a2) | ((unsigned)f2h(a3) << 16)) << 32);
      __builtin_nontemporal_store(o, reinterpret_cast<unsigned long long*>(
          Ys + (size_t)node * 32 + l8 * 4));
    }
  }
}

// ---------------- fp16 MFMA GEMM, double-buffered ----------------
// A: ALAYOUT 0 = row-major [M][K]; 1 = sliced [K/32][M][32] (BK=32=slab).
// B fp16 transposed [Npad][K]. OMODE: 0 = f32 row-major, 1 = fp16 SLICED out.

template <int RELU, int OMODE, int ALAYOUT>
__global__ __launch_bounds__(256) void k_mgemm(const unsigned short* __restrict__ Ag,
                                               const unsigned short* __restrict__ Btg,
                                               const float* __restrict__ bias,
                                               void* __restrict__ Cout,
                                               int M, int Nc, int K) {
  __shared__ unsigned short Ah[2][128 * 40];
  __shared__ unsigned short Bh[2][128 * 40];
  int tid = threadIdx.x;
  int lane = tid & 63, w = tid >> 6;
  int wr = w >> 1, wc = w & 1;
  int bm = blockIdx.x * 128, bn = blockIdx.y * 128;
  int l15 = lane & 15, kg = lane >> 4;
  int row0 = tid >> 2, kq0 = (tid & 3) * 8;
  int gm0 = bm + row0, gm1 = bm + row0 + 64;

  f32x4 zero = {0.f, 0.f, 0.f, 0.f};
  f32x4 acc[4][4];
#pragma unroll
  for (int i = 0; i < 4; i++)
#pragma unroll
    for (int j = 0; j < 4; j++) acc[i][j] = zero;

  uint4 ra0, ra1, rb0, rb1;
  const uint4 z4 = {0, 0, 0, 0};
#define LOADT(KT)                                                                     \
  {                                                                                   \
    const unsigned short* Ab = ALAYOUT                                                \
        ? Ag + (size_t)((KT) >> 5) * ((size_t)M * 32) + kq0                           \
        : Ag + (size_t)(KT) + kq0;                                                    \
    const size_t astr = ALAYOUT ? 32 : (size_t)K;                                     \
    ra0 = z4; ra1 = z4;                                                               \
    if (gm0 < M) ra0 = *reinterpret_cast<const uint4*>(Ab + (size_t)gm0 * astr);      \
    if (gm1 < M) ra1 = *reinterpret_cast<const uint4*>(Ab + (size_t)gm1 * astr);      \
    rb0 = *reinterpret_cast<const uint4*>(Btg + (size_t)(bn + row0) * K + (KT) + kq0);\
    rb1 = *reinterpret_cast<const uint4*>(Btg + (size_t)(bn + row0 + 64) * K + (KT) + kq0);\
  }
#define STORET(B)                                                       \
  {                                                                     \
    *reinterpret_cast<uint4*>(&Ah[B][row0 * 40 + kq0]) = ra0;           \
    *reinterpret_cast<uint4*>(&Ah[B][(row0 + 64) * 40 + kq0]) = ra1;    \
    *reinterpret_cast<uint4*>(&Bh[B][row0 * 40 + kq0]) = rb0;           \
    *reinterpret_cast<uint4*>(&Bh[B][(row0 + 64) * 40 + kq0]) = rb1;    \
  }

  LOADT(0);
  STORET(0);
  __syncthreads();
  int nt = K >> 5, cur = 0;
  for (int t = 0; t < nt; t++) {
    bool pf = (t + 1 < nt);
    if (pf) LOADT((t + 1) << 5);
    f16x8 fa[4], fb[4];
#pragma unroll
    for (int f = 0; f < 4; f++) {
      fa[f] = *reinterpret_cast<const f16x8*>(&Ah[cur][(wr * 64 + f * 16 + l15) * 40 + kg * 8]);
      fb[f] = *reinterpret_cast<const f16x8*>(&Bh[cur][(wc * 64 + f * 16 + l15) * 40 + kg * 8]);
    }
#pragma unroll
    for (int i = 0; i < 4; i++)
#pragma unroll
      for (int j = 0; j < 4; j++)
        acc[i][j] = __builtin_amdgcn_mfma_f32_16x16x32_f16(fa[i], fb[j], acc[i][j], 0, 0, 0);
    if (pf) STORET(cur ^ 1);
    __syncthreads();
    cur ^= 1;
  }
#undef LOADT
#undef STORET

  int r0 = kg * 4;
#pragma unroll
  for (int i = 0; i < 4; i++) {
    int gmBase = bm + wr * 64 + i * 16 + r0;
#pragma unroll
    for (int r = 0; r < 4; r++) {
      int gm = gmBase + r;
      if (gm >= M) continue;
#pragma unroll
      for (int j = 0; j < 4; j++) {
        int gn = bn + wc * 64 + j * 16 + l15;
        if (gn >= Nc) continue;
        float v = acc[i][j][r] + bias[gn];
        if (RELU) v = fmaxf(v, 0.f);
        if (OMODE == 0) {
          ((float*)Cout)[(size_t)gm * Nc + gn] = v;
        } else {  // fp16 sliced [Nc/32][M][32]
          size_t o = (size_t)(gn >> 5) * ((size_t)M * 32) + (size_t)gm * 32 + (gn & 31);
          ((unsigned short*)Cout)[o] = f2h(v);
        }
      }
    }
  }
}

// ---------------- classifier: BM=256, BN=48 (NOUT=40), sliced A, f32 out ----

__global__ __launch_bounds__(256) void k_cls(const unsigned short* __restrict__ Ag,
                                             const unsigned short* __restrict__ Btg,
                                             const float* __restrict__ bias,
                                             float* __restrict__ C, int M) {
  __shared__ unsigned short As[256 * 40];
  __shared__ unsigned short Bs[48 * 40];
  int tid = threadIdx.x;
  int lane = tid & 63, w = tid >> 6;
  int l15 = lane & 15, kg = lane >> 4;
  int bm = blockIdx.x * 256;

  f32x4 zero = {0.f, 0.f, 0.f, 0.f};
  f32x4 acc[4][3];
#pragma unroll
  for (int i = 0; i < 4; i++)
#pragma unroll
    for (int j = 0; j < 3; j++) acc[i][j] = zero;

  for (int kt = 0; kt < HID; kt += 32) {
    const unsigned short* Ab = Ag + (size_t)(kt >> 5) * ((size_t)M * 32);
#pragma unroll
    for (int it = 0; it < 4; it++) {
      int c = tid + it * 256;
      int row = c >> 2, kq = (c & 3) * 8;
      int gm = bm + row;
      uint4 v = {0, 0, 0, 0};
      if (gm < M) v = *reinterpret_cast<const uint4*>(Ab + (size_t)gm * 32 + kq);
      *reinterpret_cast<uint4*>(&As[row * 40 + kq]) = v;
    }
    if (tid < 192) {
      int row = tid >> 2, kq = (tid & 3) * 8;
      *reinterpret_cast<uint4*>(&Bs[row * 40 + kq]) =
          *reinterpret_cast<const uint4*>(Btg + (size_t)row * HID + kt + kq);
    }
    __syncthreads();
    f16x8 fa[4], fb[3];
#pragma unroll
    for (int f = 0; f < 4; f++)
      fa[f] = *reinterpret_cast<const f16x8*>(&As[(w * 64 + f * 16 + l15) * 40 + kg * 8]);
#pragma unroll
    for (int j = 0; j < 3; j++)
      fb[j] = *reinterpret_cast<const f16x8*>(&Bs[(j * 16 + l15) * 40 + kg * 8]);
#pragma unroll
    for (int i = 0; i < 4; i++)
#pragma unroll
      for (int j = 0; j < 3; j++)
        acc[i][j] = __builtin_amdgcn_mfma_f32_16x16x32_f16(fa[i], fb[j], acc[i][j], 0, 0, 0);
    __syncthreads();
  }

  int r0 = kg * 4;
#pragma unroll
  for (int i = 0; i < 4; i++) {
    int gmBase = bm + w * 64 + i * 16 + r0;
#pragma unroll
    for (int r = 0; r < 4; r++) {
      int gm = gmBase + r;
      if (gm >= M) continue;
#pragma unroll
      for (int j = 0; j < 3; j++) {
        int gn = j * 16 + l15;
        if (gn >= NOUT) continue;
        C[(size_t)gm * NOUT + gn] = acc[i][j][r] + bias[gn];
      }
    }
  }
}

// ---------------- launch ----------------

extern "C" void kernel_launch(void* const* d_in, const int* in_sizes, int n_in,
                              void* d_out, int out_size, void* d_ws, size_t ws_size,
                              hipStream_t stream) {
  (void)in_sizes; (void)n_in; (void)out_size; (void)ws_size;
  const float* x  = (const float*)d_in[0];
  const float* W1 = (const float*)d_in[1];
  const float* b1 = (const float*)d_in[2];
  const float* W2 = (const float*)d_in[3];
  const float* b2 = (const float*)d_in[4];
  const float* Wc = (const float*)d_in[5];
  const float* bc = (const float*)d_in[6];
  const int* edge = (const int*)d_in[7];
  const int* srcE = edge;
  const int* dstE = edge + NEDGES;
  float* out = (float*)d_out;

  char* ws = (char*)d_ws;
  int*   count    = (int*)(ws + 0);          // 200000 B
  int*   cursor   = (int*)(ws + 200064);
  int*   rowstart = (int*)(ws + 400128);     // per-block partial
  float* dinv     = (float*)(ws + 600320);
  int*   csr      = (int*)(ws + 800384);     // 3.2 MB
  int*   bsum     = (int*)(ws + 4000512);
  int*   boff     = (int*)(ws + 4001536);
  unsigned short* W1t = (unsigned short*)(ws + 4002560);   // 256x128 fp16
  unsigned short* W2t = (unsigned short*)(ws + 4068096);   // 256x256 fp16
  unsigned short* Wct = (unsigned short*)(ws + 4199168);   // 48x256 fp16
  unsigned short* xh  = (unsigned short*)(ws + 4264704);   // sliced 4x[N][32]
  unsigned short* aggx = (unsigned short*)(ws + 17064704); // sliced 4x[N][32]
  unsigned short* h1   = (unsigned short*)(ws + 29864704); // sliced 8x[N][32]
  unsigned short* aggh = (unsigned short*)(ws + 55464704); // sliced 8x[N][32]
  unsigned short* h2   = (unsigned short*)(ws + 81064704); // sliced 8x[N][32]

  hipMemsetAsync(ws, 0, 400128, stream);  // count + cursor

  k_pre<<<NBLK_CAST + NBLK_DEG + NBLK_PREP, 256, 0, stream>>>(
      x, xh, dstE, count, W1, W2, Wc, W1t, W2t, Wct);
  k_scan1<<<NBLK_SCAN, 256, 0, stream>>>(count, rowstart, bsum, dinv);
  k_scan2<<<1, 256, 0, stream>>>(bsum, boff);
  k_scatter<<<NBLK_DEG, 256, 0, stream>>>(srcE, dstE, rowstart, boff, cursor, csr);

  // layer 1: sliced agg (4 slabs, 2 XCDs each) + GEMM (sliced A, sliced out)
  k_aggs<4><<<NCHUNK_AGG << 2, 256, 0, stream>>>(xh, rowstart, boff, csr, dinv, aggx);
  {
    dim3 grid((NNODES + 127) / 128, HID / 128);
    k_mgemm<1, 1, 1><<<grid, 256, 0, stream>>>(aggx, W1t, b1, (void*)h1, NNODES, HID, F_IN);
  }
  // layer 2: sliced agg (8 slabs, 1 XCD each)
  k_aggs<8><<<NCHUNK_AGG << 3, 256, 0, stream>>>(h1, rowstart, boff, csr, dinv, aggh);
  {
    dim3 grid((NNODES + 127) / 128, HID / 128);
    k_mgemm<1, 1, 1><<<grid, 256, 0, stream>>>(aggh, W2t, b2, (void*)h2, NNODES, HID, HID);
  }
  // classifier (sliced A)
  k_cls<<<(NNODES + 255) / 256, 256, 0, stream>>>(h2, Wct, bc, out, NNODES);
}

// Round 11
// 367.998 us; speedup vs baseline: 1.4013x; 1.4013x over previous
//
#include <hip/hip_runtime.h>

#define NNODES 50000
#define NEDGES 800000
#define F_IN   128
#define HID    256
#define NOUT   40
#define NBLK_SCAN ((NNODES + 255) / 256)  // 196
#define NBLK_CAST 6250                     // 50000*128/4/256
#define NBLK_DEG  2048                     // partitioned: 256 chunks x 8 groups
#define NBLK_PREP 432                      // 128 (W1) + 256 (W2) + 48 (Wc)
#define EDGE_CHUNK 3125                    // 800000 / 256
#define NODES_PER_G 6250                   // 50000 / 8
#define NCHUNK_AGG 1563                    // ceil(50000 / 32)

typedef __attribute__((ext_vector_type(8))) _Float16 f16x8;
typedef __attribute__((ext_vector_type(4))) float f32x4;

__device__ __forceinline__ unsigned short f2h(float f) {
  return __builtin_bit_cast(unsigned short, (_Float16)f);
}
__device__ __forceinline__ float h2f(unsigned short u) {
  return (float)__builtin_bit_cast(_Float16, u);
}

// ------- fused: x->fp16 SLICED cast | XCD-local degree | weight transpose ---
// Sliced layout: [slice][node][32 feats], slice = feat >> 5. Slab = 3.2 MB.

__global__ __launch_bounds__(256) void k_pre(const float* __restrict__ X,
                                             unsigned short* __restrict__ Xh,
                                             const int* __restrict__ dst,
                                             int* __restrict__ count,
                                             const float* __restrict__ W1,
                                             const float* __restrict__ W2,
                                             const float* __restrict__ Wc,
                                             unsigned short* __restrict__ T1,
                                             unsigned short* __restrict__ T2,
                                             unsigned short* __restrict__ Tc) {
  int b = blockIdx.x, t = threadIdx.x;
  if (b < NBLK_CAST) {
    int i = b * 256 + t;                 // float4 unit; 32 per node row
    int node = i >> 5, c = i & 31;       // c: 4-feat chunk within row
    int slab = c >> 3, off = (c & 7) * 4;
    float4 v = *reinterpret_cast<const float4*>(X + (size_t)i * 4);
    ushort4 o;
    o.x = f2h(v.x); o.y = f2h(v.y); o.z = f2h(v.z); o.w = f2h(v.w);
    *reinterpret_cast<ushort4*>(Xh + (size_t)slab * (NNODES * 32) +
                                (size_t)node * 32 + off) = o;
  } else if (b < NBLK_CAST + NBLK_DEG) {
    int db = b - NBLK_CAST;
    int g = b & 7;                 // hardware XCD (round-robin heuristic)
    int chunk = db >> 3;           // 0..255
    int lo = g * NODES_PER_G, hi = lo + NODES_PER_G;
    int base = chunk * EDGE_CHUNK;
    for (int i = base + t; i < base + EDGE_CHUNK; i += 256) {
      int d = dst[i];
      if (d >= lo && d < hi) atomicAdd(&count[d], 1);
    }
  } else {
    int pb = b - NBLK_CAST - NBLK_DEG;  // 0..431
    if (pb < 128) {                     // W1 [128][256] -> T1 [256][128]
      int idx = pb * 256 + t;
      int n = idx >> 7, k = idx & 127;
      T1[idx] = f2h(W1[(size_t)k * HID + n]);
    } else if (pb < 384) {              // W2 [256][256] -> T2 [256][256]
      int idx = (pb - 128) * 256 + t;
      int n = idx >> 8, k = idx & 255;
      T2[idx] = f2h(W2[(size_t)k * HID + n]);
    } else {                            // Wc [256][40] -> Tc [48][256] zero-pad
      int idx = (pb - 384) * 256 + t;
      int n = idx >> 8, k = idx & 255;
      float v = (n < NOUT) ? Wc[(size_t)k * NOUT + n] : 0.f;
      Tc[idx] = f2h(v);
    }
  }
}

// ---------------- CSR scan ----------------

__global__ __launch_bounds__(256) void k_scan1(const int* __restrict__ count,
                                               int* __restrict__ rowstart,
                                               int* __restrict__ bsum,
                                               float* __restrict__ dinv) {
  __shared__ int tmp[256];
  int t = threadIdx.x;
  int i = blockIdx.x * 256 + t;
  int v = (i < NNODES) ? count[i] : 0;
  if (i < NNODES) dinv[i] = rsqrtf((float)(v + 1));  // +1 self-loop
  tmp[t] = v;
  __syncthreads();
  for (int off = 1; off < 256; off <<= 1) {
    int x = (t >= off) ? tmp[t - off] : 0;
    __syncthreads();
    tmp[t] += x;
    __syncthreads();
  }
  if (i < NNODES) rowstart[i] = tmp[t] - v;  // exclusive within block
  if (t == 255) bsum[blockIdx.x] = tmp[255];
}

__global__ __launch_bounds__(256) void k_scan2(const int* __restrict__ bsum,
                                               int* __restrict__ boff) {
  __shared__ int tmp[256];
  int t = threadIdx.x;
  int v = (t < NBLK_SCAN) ? bsum[t] : 0;
  tmp[t] = v;
  __syncthreads();
  for (int off = 1; off < 256; off <<= 1) {
    int x = (t >= off) ? tmp[t - off] : 0;
    __syncthreads();
    tmp[t] += x;
    __syncthreads();
  }
  if (t < NBLK_SCAN) boff[t] = tmp[t] - v;  // exclusive
}

// ---------------- XCD-local scatter ----------------

__global__ __launch_bounds__(256) void k_scatter(const int* __restrict__ src,
                                                 const int* __restrict__ dst,
                                                 const int* __restrict__ rowstart,
                                                 const int* __restrict__ boff,
                                                 int* __restrict__ cursor,
                                                 int* __restrict__ csr) {
  int g = blockIdx.x & 7;
  int chunk = blockIdx.x >> 3;
  int lo = g * NODES_PER_G, hi = lo + NODES_PER_G;
  int base = chunk * EDGE_CHUNK;
  for (int i = base + threadIdx.x; i < base + EDGE_CHUNK; i += 256) {
    int d = dst[i];
    if (d >= lo && d < hi) {
      int p = rowstart[d] + boff[d >> 8] + atomicAdd(&cursor[d], 1);
      csr[p] = src[i];
    }
  }
}

// ---------------- feature-sliced XCD-resident aggregation, group-per-node ---
// X,Y sliced [NSLICE][N][32] fp16; blocks with blockIdx&(NSLICE-1)==g touch
// only slab g (3.2 MB -> one XCD's L2). ONE 8-lane group per node: each lane
// owns 4 feats, accumulates over all the node's edges (no cross-lane reduce,
// no serial node loop). 4x unroll -> 32 independent 64B gathers in flight
// per wave. csr/dinv reads are NSLICE-x redundant (cheap, L1/L2-resident).

template <int NSLICE>
__global__ __launch_bounds__(256) void k_aggs(const unsigned short* __restrict__ X,
                                              const int* __restrict__ rowstart,
                                              const int* __restrict__ boff,
                                              const int* __restrict__ csr,
                                              const float* __restrict__ dinv,
                                              unsigned short* __restrict__ Y) {
  constexpr int SSH = (NSLICE == 8) ? 3 : 2;
  int slice = blockIdx.x & (NSLICE - 1);
  int chunk = blockIdx.x >> SSH;
  const unsigned short* Xs = X + (size_t)slice * (NNODES * 32);
  unsigned short* Ys = Y + (size_t)slice * (NNODES * 32);
  int wave = threadIdx.x >> 6, lane = threadIdx.x & 63;
  int grp = lane >> 3, l8 = lane & 7;
  int node = (chunk * 4 + wave) * 8 + grp;   // one node per 8-lane group
  bool alive = node < NNODES;
  float di = alive ? dinv[node] : 0.f;
  int e = 0, end = 0;
  if (alive) {
    e = rowstart[node] + boff[node >> 8];
    end = (node + 1 < NNODES) ? rowstart[node + 1] + boff[(node + 1) >> 8] : NEDGES;
  }
  float a0 = 0.f, a1 = 0.f, a2 = 0.f, a3 = 0.f;
  const unsigned short* Xl = Xs + l8 * 4;    // lane's 4-feat column base
  for (; e + 4 <= end; e += 4) {
    int s0 = csr[e], s1 = csr[e + 1], s2 = csr[e + 2], s3 = csr[e + 3];
    float w0 = dinv[s0] * di, w1 = dinv[s1] * di;
    float w2 = dinv[s2] * di, w3 = dinv[s3] * di;
    uint2 v0 = *reinterpret_cast<const uint2*>(Xl + (size_t)s0 * 32);
    uint2 v1 = *reinterpret_cast<const uint2*>(Xl + (size_t)s1 * 32);
    uint2 v2 = *reinterpret_cast<const uint2*>(Xl + (size_t)s2 * 32);
    uint2 v3 = *reinterpret_cast<const uint2*>(Xl + (size_t)s3 * 32);
    a0 = fmaf(h2f((unsigned short)v0.x), w0, a0);
    a1 = fmaf(h2f((unsigned short)(v0.x >> 16)), w0, a1);
    a2 = fmaf(h2f((unsigned short)v0.y), w0, a2);
    a3 = fmaf(h2f((unsigned short)(v0.y >> 16)), w0, a3);
    a0 = fmaf(h2f((unsigned short)v1.x), w1, a0);
    a1 = fmaf(h2f((unsigned short)(v1.x >> 16)), w1, a1);
    a2 = fmaf(h2f((unsigned short)v1.y), w1, a2);
    a3 = fmaf(h2f((unsigned short)(v1.y >> 16)), w1, a3);
    a0 = fmaf(h2f((unsigned short)v2.x), w2, a0);
    a1 = fmaf(h2f((unsigned short)(v2.x >> 16)), w2, a1);
    a2 = fmaf(h2f((unsigned short)v2.y), w2, a2);
    a3 = fmaf(h2f((unsigned short)(v2.y >> 16)), w2, a3);
    a0 = fmaf(h2f((unsigned short)v3.x), w3, a0);
    a1 = fmaf(h2f((unsigned short)(v3.x >> 16)), w3, a1);
    a2 = fmaf(h2f((unsigned short)v3.y), w3, a2);
    a3 = fmaf(h2f((unsigned short)(v3.y >> 16)), w3, a3);
  }
  for (; e < end; ++e) {
    int s = csr[e];
    float w = dinv[s] * di;
    uint2 v = *reinterpret_cast<const uint2*>(Xl + (size_t)s * 32);
    a0 = fmaf(h2f((unsigned short)v.x), w, a0);
    a1 = fmaf(h2f((unsigned short)(v.x >> 16)), w, a1);
    a2 = fmaf(h2f((unsigned short)v.y), w, a2);
    a3 = fmaf(h2f((unsigned short)(v.y >> 16)), w, a3);
  }
  if (alive) {  // self-loop + 8B store (64B/group contiguous)
    uint2 v = *reinterpret_cast<const uint2*>(Xl + (size_t)node * 32);
    float dd = di * di;
    a0 = fmaf(h2f((unsigned short)v.x), dd, a0);
    a1 = fmaf(h2f((unsigned short)(v.x >> 16)), dd, a1);
    a2 = fmaf(h2f((unsigned short)v.y), dd, a2);
    a3 = fmaf(h2f((unsigned short)(v.y >> 16)), dd, a3);
    unsigned long long o =
        (unsigned long long)((unsigned)f2h(a0) | ((unsigned)f2h(a1) << 16)) |
        ((unsigned long long)((unsigned)f2h(a2) | ((unsigned)f2h(a3) << 16)) << 32);
    __builtin_nontemporal_store(o, reinterpret_cast<unsigned long long*>(
        Ys + (size_t)node * 32 + l8 * 4));
  }
}

// ---------------- fp16 MFMA GEMM, double-buffered ----------------
// A: ALAYOUT 0 = row-major [M][K]; 1 = sliced [K/32][M][32] (BK=32=slab).
// B fp16 transposed [Npad][K]. OMODE: 0 = f32 row-major, 1 = fp16 SLICED out.

template <int RELU, int OMODE, int ALAYOUT>
__global__ __launch_bounds__(256) void k_mgemm(const unsigned short* __restrict__ Ag,
                                               const unsigned short* __restrict__ Btg,
                                               const float* __restrict__ bias,
                                               void* __restrict__ Cout,
                                               int M, int Nc, int K) {
  __shared__ unsigned short Ah[2][128 * 40];
  __shared__ unsigned short Bh[2][128 * 40];
  int tid = threadIdx.x;
  int lane = tid & 63, w = tid >> 6;
  int wr = w >> 1, wc = w & 1;
  int bm = blockIdx.x * 128, bn = blockIdx.y * 128;
  int l15 = lane & 15, kg = lane >> 4;
  int row0 = tid >> 2, kq0 = (tid & 3) * 8;
  int gm0 = bm + row0, gm1 = bm + row0 + 64;

  f32x4 zero = {0.f, 0.f, 0.f, 0.f};
  f32x4 acc[4][4];
#pragma unroll
  for (int i = 0; i < 4; i++)
#pragma unroll
    for (int j = 0; j < 4; j++) acc[i][j] = zero;

  uint4 ra0, ra1, rb0, rb1;
  const uint4 z4 = {0, 0, 0, 0};
#define LOADT(KT)                                                                     \
  {                                                                                   \
    const unsigned short* Ab = ALAYOUT                                                \
        ? Ag + (size_t)((KT) >> 5) * ((size_t)M * 32) + kq0                           \
        : Ag + (size_t)(KT) + kq0;                                                    \
    const size_t astr = ALAYOUT ? 32 : (size_t)K;                                     \
    ra0 = z4; ra1 = z4;                                                               \
    if (gm0 < M) ra0 = *reinterpret_cast<const uint4*>(Ab + (size_t)gm0 * astr);      \
    if (gm1 < M) ra1 = *reinterpret_cast<const uint4*>(Ab + (size_t)gm1 * astr);      \
    rb0 = *reinterpret_cast<const uint4*>(Btg + (size_t)(bn + row0) * K + (KT) + kq0);\
    rb1 = *reinterpret_cast<const uint4*>(Btg + (size_t)(bn + row0 + 64) * K + (KT) + kq0);\
  }
#define STORET(B)                                                       \
  {                                                                     \
    *reinterpret_cast<uint4*>(&Ah[B][row0 * 40 + kq0]) = ra0;           \
    *reinterpret_cast<uint4*>(&Ah[B][(row0 + 64) * 40 + kq0]) = ra1;    \
    *reinterpret_cast<uint4*>(&Bh[B][row0 * 40 + kq0]) = rb0;           \
    *reinterpret_cast<uint4*>(&Bh[B][(row0 + 64) * 40 + kq0]) = rb1;    \
  }

  LOADT(0);
  STORET(0);
  __syncthreads();
  int nt = K >> 5, cur = 0;
  for (int t = 0; t < nt; t++) {
    bool pf = (t + 1 < nt);
    if (pf) LOADT((t + 1) << 5);
    f16x8 fa[4], fb[4];
#pragma unroll
    for (int f = 0; f < 4; f++) {
      fa[f] = *reinterpret_cast<const f16x8*>(&Ah[cur][(wr * 64 + f * 16 + l15) * 40 + kg * 8]);
      fb[f] = *reinterpret_cast<const f16x8*>(&Bh[cur][(wc * 64 + f * 16 + l15) * 40 + kg * 8]);
    }
#pragma unroll
    for (int i = 0; i < 4; i++)
#pragma unroll
      for (int j = 0; j < 4; j++)
        acc[i][j] = __builtin_amdgcn_mfma_f32_16x16x32_f16(fa[i], fb[j], acc[i][j], 0, 0, 0);
    if (pf) STORET(cur ^ 1);
    __syncthreads();
    cur ^= 1;
  }
#undef LOADT
#undef STORET

  int r0 = kg * 4;
#pragma unroll
  for (int i = 0; i < 4; i++) {
    int gmBase = bm + wr * 64 + i * 16 + r0;
#pragma unroll
    for (int r = 0; r < 4; r++) {
      int gm = gmBase + r;
      if (gm >= M) continue;
#pragma unroll
      for (int j = 0; j < 4; j++) {
        int gn = bn + wc * 64 + j * 16 + l15;
        if (gn >= Nc) continue;
        float v = acc[i][j][r] + bias[gn];
        if (RELU) v = fmaxf(v, 0.f);
        if (OMODE == 0) {
          ((float*)Cout)[(size_t)gm * Nc + gn] = v;
        } else {  // fp16 sliced [Nc/32][M][32]
          size_t o = (size_t)(gn >> 5) * ((size_t)M * 32) + (size_t)gm * 32 + (gn & 31);
          ((unsigned short*)Cout)[o] = f2h(v);
        }
      }
    }
  }
}

// ---------------- classifier: BM=256, BN=48 (NOUT=40), sliced A, f32 out ----

__global__ __launch_bounds__(256) void k_cls(const unsigned short* __restrict__ Ag,
                                             const unsigned short* __restrict__ Btg,
                                             const float* __restrict__ bias,
                                             float* __restrict__ C, int M) {
  __shared__ unsigned short As[256 * 40];
  __shared__ unsigned short Bs[48 * 40];
  int tid = threadIdx.x;
  int lane = tid & 63, w = tid >> 6;
  int l15 = lane & 15, kg = lane >> 4;
  int bm = blockIdx.x * 256;

  f32x4 zero = {0.f, 0.f, 0.f, 0.f};
  f32x4 acc[4][3];
#pragma unroll
  for (int i = 0; i < 4; i++)
#pragma unroll
    for (int j = 0; j < 3; j++) acc[i][j] = zero;

  for (int kt = 0; kt < HID; kt += 32) {
    const unsigned short* Ab = Ag + (size_t)(kt >> 5) * ((size_t)M * 32);
#pragma unroll
    for (int it = 0; it < 4; it++) {
      int c = tid + it * 256;
      int row = c >> 2, kq = (c & 3) * 8;
      int gm = bm + row;
      uint4 v = {0, 0, 0, 0};
      if (gm < M) v = *reinterpret_cast<const uint4*>(Ab + (size_t)gm * 32 + kq);
      *reinterpret_cast<uint4*>(&As[row * 40 + kq]) = v;
    }
    if (tid < 192) {
      int row = tid >> 2, kq = (tid & 3) * 8;
      *reinterpret_cast<uint4*>(&Bs[row * 40 + kq]) =
          *reinterpret_cast<const uint4*>(Btg + (size_t)row * HID + kt + kq);
    }
    __syncthreads();
    f16x8 fa[4], fb[3];
#pragma unroll
    for (int f = 0; f < 4; f++)
      fa[f] = *reinterpret_cast<const f16x8*>(&As[(w * 64 + f * 16 + l15) * 40 + kg * 8]);
#pragma unroll
    for (int j = 0; j < 3; j++)
      fb[j] = *reinterpret_cast<const f16x8*>(&Bs[(j * 16 + l15) * 40 + kg * 8]);
#pragma unroll
    for (int i = 0; i < 4; i++)
#pragma unroll
      for (int j = 0; j < 3; j++)
        acc[i][j] = __builtin_amdgcn_mfma_f32_16x16x32_f16(fa[i], fb[j], acc[i][j], 0, 0, 0);
    __syncthreads();
  }

  int r0 = kg * 4;
#pragma unroll
  for (int i = 0; i < 4; i++) {
    int gmBase = bm + w * 64 + i * 16 + r0;
#pragma unroll
    for (int r = 0; r < 4; r++) {
      int gm = gmBase + r;
      if (gm >= M) continue;
#pragma unroll
      for (int j = 0; j < 3; j++) {
        int gn = j * 16 + l15;
        if (gn >= NOUT) continue;
        C[(size_t)gm * NOUT + gn] = acc[i][j][r] + bias[gn];
      }
    }
  }
}

// ---------------- launch ----------------

extern "C" void kernel_launch(void* const* d_in, const int* in_sizes, int n_in,
                              void* d_out, int out_size, void* d_ws, size_t ws_size,
                              hipStream_t stream) {
  (void)in_sizes; (void)n_in; (void)out_size; (void)ws_size;
  const float* x  = (const float*)d_in[0];
  const float* W1 = (const float*)d_in[1];
  const float* b1 = (const float*)d_in[2];
  const float* W2 = (const float*)d_in[3];
  const float* b2 = (const float*)d_in[4];
  const float* Wc = (const float*)d_in[5];
  const float* bc = (const float*)d_in[6];
  const int* edge = (const int*)d_in[7];
  const int* srcE = edge;
  const int* dstE = edge + NEDGES;
  float* out = (float*)d_out;

  char* ws = (char*)d_ws;
  int*   count    = (int*)(ws + 0);          // 200000 B
  int*   cursor   = (int*)(ws + 200064);
  int*   rowstart = (int*)(ws + 400128);     // per-block partial
  float* dinv     = (float*)(ws + 600320);
  int*   csr      = (int*)(ws + 800384);     // 3.2 MB
  int*   bsum     = (int*)(ws + 4000512);
  int*   boff     = (int*)(ws + 4001536);
  unsigned short* W1t = (unsigned short*)(ws + 4002560);   // 256x128 fp16
  unsigned short* W2t = (unsigned short*)(ws + 4068096);   // 256x256 fp16
  unsigned short* Wct = (unsigned short*)(ws + 4199168);   // 48x256 fp16
  unsigned short* xh  = (unsigned short*)(ws + 4264704);   // sliced 4x[N][32]
  unsigned short* aggx = (unsigned short*)(ws + 17064704); // sliced 4x[N][32]
  unsigned short* h1   = (unsigned short*)(ws + 29864704); // sliced 8x[N][32]
  unsigned short* aggh = (unsigned short*)(ws + 55464704); // sliced 8x[N][32]
  unsigned short* h2   = (unsigned short*)(ws + 81064704); // sliced 8x[N][32]

  hipMemsetAsync(ws, 0, 400128, stream);  // count + cursor

  k_pre<<<NBLK_CAST + NBLK_DEG + NBLK_PREP, 256, 0, stream>>>(
      x, xh, dstE, count, W1, W2, Wc, W1t, W2t, Wct);
  k_scan1<<<NBLK_SCAN, 256, 0, stream>>>(count, rowstart, bsum, dinv);
  k_scan2<<<1, 256, 0, stream>>>(bsum, boff);
  k_scatter<<<NBLK_DEG, 256, 0, stream>>>(srcE, dstE, rowstart, boff, cursor, csr);

  // layer 1: sliced agg (4 slabs) + GEMM (sliced A, sliced out)
  k_aggs<4><<<NCHUNK_AGG << 2, 256, 0, stream>>>(xh, rowstart, boff, csr, dinv, aggx);
  {
    dim3 grid((NNODES + 127) / 128, HID / 128);
    k_mgemm<1, 1, 1><<<grid, 256, 0, stream>>>(aggx, W1t, b1, (void*)h1, NNODES, HID, F_IN);
  }
  // layer 2: sliced agg (8 slabs, 1 XCD each)
  k_aggs<8><<<NCHUNK_AGG << 3, 256, 0, stream>>>(h1, rowstart, boff, csr, dinv, aggh);
  {
    dim3 grid((NNODES + 127) / 128, HID / 128);
    k_mgemm<1, 1, 1><<<grid, 256, 0, stream>>>(aggh, W2t, b2, (void*)h2, NNODES, HID, HID);
  }
  // classifier (sliced A)
  k_cls<<<(NNODES + 255) / 256, 256, 0, stream>>>(h2, Wct, bc, out, NNODES);
}